// Round 1
// 163.227 us; speedup vs baseline: 1.4917x; 1.4917x over previous
//
#include <hip/hip_runtime.h>
#include <cstdint>
#include <cstddef>

// Problem constants (from reference setup_inputs)
#define C_ 4
#define B_ 128
#define G_ 2048
#define S_ 32
#define L_ 3
#define NSTEP_ 3
#define GAMMA_ 0.01f
// exp((x)*100) == exp2((x)*144.2695...), gamma*ln(a) = gamma*ln2*log2(a)
#define INVG_LOG2E_ 144.26950408889634f
#define GAMMA_LN2_ 0.0069314718055994530942f

// Slot layout: slot s occupies uint indices [s*128, s*128+128) = 512 B,
// with 8 atomic "banks" at 64 B stride (slots[s*128 + k*16]).
// Banking spreads same-address atomicMax traffic across 8 cache lines.
__device__ __forceinline__ float slot_max(const uint32_t* slots, int slot) {
  float m = 0.0f;
#pragma unroll
  for (int k = 0; k < 8; ++k)
    m = fmaxf(m, __uint_as_float(slots[slot * 128 + k * 16]));
  return m;
}

// ---------------------------------------------------------------------------
// k_init: A[c,g,b] = x[b,g]  (transpose + broadcast over clauses)
// block (32,8), grid (G/32, B/32, C). LDS-tiled to keep both sides coalesced.
// ---------------------------------------------------------------------------
__global__ __launch_bounds__(256) void k_init(const float* __restrict__ x,
                                              float* __restrict__ A) {
  __shared__ float tile[32][33];
  const int g0 = blockIdx.x * 32, b0 = blockIdx.y * 32, c = blockIdx.z;
  const int tx = threadIdx.x;
  for (int i = threadIdx.y; i < 32; i += 8)
    tile[i][tx] = x[(size_t)(b0 + i) * G_ + g0 + tx];  // tile[b-b0][g-g0]
  __syncthreads();
  for (int j = threadIdx.y; j < 32; j += 8)
    A[((size_t)c * G_ + g0 + j) * B_ + b0 + tx] = tile[tx][j];
}

// ---------------------------------------------------------------------------
// k_gather: one (c,g) per block, 128 threads = b lanes, 8192 blocks.
// body[s] = prod_l A[c, I[c,g,s,l], b] (raw); scale^3 folded into the
// exponent constant: lse = m*s3 + gamma*ln2*log2(sum exp2((body-m)*s3*K)).
// XCD-bijective swizzle: each XCD's L2 sees exactly one clause slice (1 MB).
// Block max via shfl_xor wave reduce -> 1 banked global atomic per block.
// ---------------------------------------------------------------------------
__global__ __launch_bounds__(128) void k_gather(const float* __restrict__ A,
                                                const int* __restrict__ Idx,
                                                float* __restrict__ Lout,
                                                uint32_t* slots,
                                                int prev_slot, int out_slot) {
  __shared__ int sidx[S_ * L_];
  __shared__ float wmax[2];
  const int tid = threadIdx.x;
  const int bid = blockIdx.x;
  // bijective XCD swizzle (8192 % 8 == 0): XCD k handles cg in [k*1024,(k+1)*1024)
  const int cg = ((bid & 7) << 10) | (bid >> 3);
  const int c = cg >> 11;  // / G_

  if (tid < S_ * L_) sidx[tid] = Idx[(size_t)cg * (S_ * L_) + tid];
  const float mprev = slot_max(slots, prev_slot);
  const float scale = (mprev > 1.0f) ? (1.0f / mprev) : 1.0f;
  const float s3 = scale * scale * scale;
  __syncthreads();

  const float* Ac = A + (size_t)c * (G_ * B_) + tid;
  float body[S_];
#pragma unroll
  for (int s = 0; s < S_; ++s) {
    const float v0 = Ac[(size_t)sidx[3 * s + 0] * B_];
    const float v1 = Ac[(size_t)sidx[3 * s + 1] * B_];
    const float v2 = Ac[(size_t)sidx[3 * s + 2] * B_];
    body[s] = v0 * v1 * v2;  // raw product; scale^3 folded below
  }
  float m = body[0];
#pragma unroll
  for (int s = 1; s < S_; ++s) m = fmaxf(m, body[s]);
  const float K = s3 * INVG_LOG2E_;
  float acc = 0.0f;
#pragma unroll
  for (int s = 0; s < S_; ++s) acc += exp2f((body[s] - m) * K);
  const float lse = m * s3 + GAMMA_LN2_ * log2f(acc);
  Lout[(size_t)cg * B_ + tid] = lse;

  // block max: 64-lane butterfly reduce, then cross-wave via LDS
  float t = lse;
#pragma unroll
  for (int off = 32; off >= 1; off >>= 1) t = fmaxf(t, __shfl_xor(t, off));
  if ((tid & 63) == 0) wmax[tid >> 6] = t;
  __syncthreads();
  if (tid == 0)
    atomicMax(slots + out_slot * 128 + (bid & 7) * 16,
              __float_as_uint(fmaxf(wmax[0], wmax[1])));
}

// ---------------------------------------------------------------------------
// k_elem: R = A*sprev; ce = lse1*s1; A = 2-elem softor(R, ce).
// Exactly one float4 per thread: 1024 blocks x 256 threads x 4 = C*G*B.
// ---------------------------------------------------------------------------
__global__ __launch_bounds__(256) void k_elem(float* __restrict__ A,
                                              const float* __restrict__ Lin,
                                              uint32_t* slots,
                                              int prev_slot, int m1_slot,
                                              int out_slot) {
  __shared__ float wmax[4];
  const float mprev = slot_max(slots, prev_slot);
  const float sprev = (mprev > 1.0f) ? (1.0f / mprev) : 1.0f;
  const float m1 = slot_max(slots, m1_slot);
  const float s1 = (m1 > 1.0f) ? (1.0f / m1) : 1.0f;

  const int e = (blockIdx.x * 256 + threadIdx.x) * 4;
  const float4 Rv = *reinterpret_cast<const float4*>(A + e);
  const float4 Lv = *reinterpret_cast<const float4*>(Lin + e);

  float r[4] = {Rv.x, Rv.y, Rv.z, Rv.w};
  float l[4] = {Lv.x, Lv.y, Lv.z, Lv.w};
  float o[4];
  float tmax = 0.0f;
#pragma unroll
  for (int k = 0; k < 4; ++k) {
    const float R = r[k] * sprev;
    const float ce = l[k] * s1;
    const float M = fmaxf(R, ce);
    const float mn = fminf(R, ce);
    // M + gamma*log(1 + exp((mn-M)/gamma)) in exp2/log2 form
    const float lse2 =
        M + GAMMA_LN2_ * log2f(1.0f + exp2f((mn - M) * INVG_LOG2E_));
    o[k] = lse2;
    tmax = fmaxf(tmax, lse2);
  }
  *reinterpret_cast<float4*>(A + e) = make_float4(o[0], o[1], o[2], o[3]);

  float t = tmax;
#pragma unroll
  for (int off = 32; off >= 1; off >>= 1) t = fmaxf(t, __shfl_xor(t, off));
  if ((threadIdx.x & 63) == 0) wmax[threadIdx.x >> 6] = t;
  __syncthreads();
  if (threadIdx.x == 0) {
    const float bm =
        fmaxf(fmaxf(wmax[0], wmax[1]), fmaxf(wmax[2], wmax[3]));
    atomicMax(slots + out_slot * 128 + (blockIdx.x & 7) * 16,
              __float_as_uint(bm));
  }
}

// ---------------------------------------------------------------------------
// k_out: out[c,b,g] = A[c,g,b] * final_scale  (LDS-tiled transpose back)
// ---------------------------------------------------------------------------
__global__ __launch_bounds__(256) void k_out(const float* __restrict__ A,
                                             float* __restrict__ out,
                                             const uint32_t* __restrict__ slots,
                                             int mslot) {
  __shared__ float tile[32][33];
  const float mfin = slot_max(slots, mslot);
  const float sc = (mfin > 1.0f) ? (1.0f / mfin) : 1.0f;
  const int g0 = blockIdx.x * 32, b0 = blockIdx.y * 32, c = blockIdx.z;
  const int tx = threadIdx.x;
  for (int j = threadIdx.y; j < 32; j += 8)
    tile[j][tx] = A[((size_t)c * G_ + g0 + j) * B_ + b0 + tx];  // tile[g][b]
  __syncthreads();
  for (int i = threadIdx.y; i < 32; i += 8)
    out[((size_t)c * B_ + b0 + i) * G_ + g0 + tx] = tile[tx][i] * sc;
}

extern "C" void kernel_launch(void* const* d_in, const int* in_sizes, int n_in,
                              void* d_out, int out_size, void* d_ws,
                              size_t ws_size, hipStream_t stream) {
  const float* x = (const float*)d_in[0];  // [B,G]
  const int* Idx = (const int*)d_in[1];    // [C,G,S,L]
  float* out = (float*)d_out;              // [C,B,G]

  char* ws = (char*)d_ws;
  uint32_t* slots = (uint32_t*)ws;  // 7 slots x 512 B (8 banks x 64 B each)
  float* A = (float*)(ws + 4096);                                  // [C,G,B] 4MB
  float* Lb = (float*)(ws + 4096 + (size_t)C_ * G_ * B_ * 4);      // [C,G,B] 4MB

  hipMemsetAsync(slots, 0, 4096, stream);

  dim3 tb(32, 8);
  k_init<<<dim3(G_ / 32, B_ / 32, C_), tb, 0, stream>>>(x, A);

  for (int step = 0; step < NSTEP_; ++step) {
    const int prev = 2 * step;      // m2 of previous step (all-zero -> scale 1)
    const int m1s = 2 * step + 1;
    const int m2s = 2 * step + 2;
    k_gather<<<C_ * G_, 128, 0, stream>>>(A, Idx, Lb, slots, prev, m1s);
    k_elem<<<(C_ * G_ * B_) / (256 * 4), 256, 0, stream>>>(A, Lb, slots, prev,
                                                           m1s, m2s);
  }

  k_out<<<dim3(G_ / 32, B_ / 32, C_), tb, 0, stream>>>(A, out, slots,
                                                       2 * NSTEP_);
}